// Round 8
// baseline (250.960 us; speedup 1.0000x reference)
//
#include <hip/hip_runtime.h>

#define GLOBAL_AS __attribute__((address_space(1)))
#define LDS_AS    __attribute__((address_space(3)))

typedef int   i32x4  __attribute__((ext_vector_type(4)));
typedef int   i32x8  __attribute__((ext_vector_type(8)));
typedef float f32x16 __attribute__((ext_vector_type(16)));

// ---------- kernel 1: fused L2 normalize -> fp8 e4m3 of (x * 32 / ||row||) ----------
__global__ __launch_bounds__(256) void l2norm_fp8_kernel(const float* __restrict__ audio,
                                                         const float* __restrict__ visual,
                                                         unsigned char* __restrict__ out) {
    const int gw = blockIdx.x * 4 + (threadIdx.x >> 6);  // global row 0..24575
    const int l  = threadIdx.x & 63;
    const float* src = (gw < 16384) ? (audio + (size_t)gw * 768)
                                    : (visual + ((size_t)gw - 16384) * 768);
    const float4* p = (const float4*)src;
    float4 a = p[l], b = p[l + 64], c = p[l + 128];
    float ss = a.x * a.x + a.y * a.y + a.z * a.z + a.w * a.w
             + b.x * b.x + b.y * b.y + b.z * b.z + b.w * b.w
             + c.x * c.x + c.y * c.y + c.z * c.z + c.w * c.w;
#pragma unroll
    for (int m = 1; m < 64; m <<= 1) ss += __shfl_xor(ss, m, 64);
    const float s = 32.0f / fmaxf(sqrtf(ss), 1e-12f);
    unsigned int* o = (unsigned int*)(out + (size_t)gw * 768);
    int d0 = __builtin_amdgcn_cvt_pk_fp8_f32(a.x * s, a.y * s, 0, false);
    d0     = __builtin_amdgcn_cvt_pk_fp8_f32(a.z * s, a.w * s, d0, true);
    int d1 = __builtin_amdgcn_cvt_pk_fp8_f32(b.x * s, b.y * s, 0, false);
    d1     = __builtin_amdgcn_cvt_pk_fp8_f32(b.z * s, b.w * s, d1, true);
    int d2 = __builtin_amdgcn_cvt_pk_fp8_f32(c.x * s, c.y * s, 0, false);
    d2     = __builtin_amdgcn_cvt_pk_fp8_f32(c.z * s, c.w * s, d2, true);
    o[l] = (unsigned int)d0; o[l + 64] = (unsigned int)d1; o[l + 128] = (unsigned int)d2;
}

// ---------- kernel 2: 256x256-tile fp8 GEMM (mfma_scale 32x32x64), fused row-max ----
// A: 16384x768 fp8, V: 8192x768 fp8. Block = 512 threads, 8 waves (2 wm x 4 wn),
// wave tile 128x64; block tile = 256 audio rows x one clip (256 visual rows).
// LDS: RING of 4 buffers x 32 KiB (A 16K + B 16K), frag-slot layout:
//   A slot16 = wm<<9 | mi<<7 | h<<6 | lane ; element (row = wm*128+mi*32+(lane&31),
//   kb = (lane>>5)*32 + h*16). B same with wn(4),ni(2) at +16384.
// -> every ds_read_b128 is base + lane*16 (linear, 0 bank conflicts); staging dest
// is linear; the permutation lives in the per-lane GLOBAL source address.
// Loop: 2 K-tiles per iteration, 2 barriers per iteration (1/tile), counted
// vmcnt(8) at entry (waits only the stage issued 2 iterations back; never drains).
// NOTE: acc = 128 AGPRs; launch_bounds min-waves must stay 2 (R5: 4 -> spill, 8GB
// scratch traffic, 5.5x slower).

#define STAGE(T) do {                                                                 \
    const size_t _ko = (size_t)(T) * 64;                                              \
    char* _d = smem + ((T) & 3) * 32768 + tid * 16;                                   \
    __builtin_amdgcn_global_load_lds((GLOBAL_AS void*)(aStage + _ko),                 \
                                     (LDS_AS void*)(_d), 16, 0, 0);                   \
    __builtin_amdgcn_global_load_lds((GLOBAL_AS void*)(aStage + 98304 + _ko),         \
                                     (LDS_AS void*)(_d + 8192), 16, 0, 0);            \
    __builtin_amdgcn_global_load_lds((GLOBAL_AS void*)(vStage + _ko),                 \
                                     (LDS_AS void*)(_d + 16384), 16, 0, 0);           \
    __builtin_amdgcn_global_load_lds((GLOBAL_AS void*)(vStage + 98304 + _ko),         \
                                     (LDS_AS void*)(_d + 24576), 16, 0, 0);           \
  } while (0)

#define READT(T) do {                                                                 \
    const char* _b = smem + ((T) & 3) * 32768;                                        \
    const char* _a = _b + wm * 8192 + l16;                                            \
    const char* _v = _b + 16384 + wn * 4096 + l16;                                    \
    fa0 = rd_frag2(_a);                                                               \
    fa1 = rd_frag2(_a + 2048);                                                        \
    fa2 = rd_frag2(_a + 4096);                                                        \
    fa3 = rd_frag2(_a + 6144);                                                        \
    fb0 = rd_frag2(_v);                                                               \
    fb1 = rd_frag2(_v + 2048);                                                        \
  } while (0)

#define MFMA8() do {                                                                  \
    __builtin_amdgcn_s_setprio(1);                                                    \
    acc[0][0] = __builtin_amdgcn_mfma_scale_f32_32x32x64_f8f6f4(                      \
        fa0, fb0, acc[0][0], 0, 0, 0, 0x7F7F7F7F, 0, 0x7F7F7F7F);                     \
    acc[1][0] = __builtin_amdgcn_mfma_scale_f32_32x32x64_f8f6f4(                      \
        fa1, fb0, acc[1][0], 0, 0, 0, 0x7F7F7F7F, 0, 0x7F7F7F7F);                     \
    acc[2][0] = __builtin_amdgcn_mfma_scale_f32_32x32x64_f8f6f4(                      \
        fa2, fb0, acc[2][0], 0, 0, 0, 0x7F7F7F7F, 0, 0x7F7F7F7F);                     \
    acc[3][0] = __builtin_amdgcn_mfma_scale_f32_32x32x64_f8f6f4(                      \
        fa3, fb0, acc[3][0], 0, 0, 0, 0x7F7F7F7F, 0, 0x7F7F7F7F);                     \
    acc[0][1] = __builtin_amdgcn_mfma_scale_f32_32x32x64_f8f6f4(                      \
        fa0, fb1, acc[0][1], 0, 0, 0, 0x7F7F7F7F, 0, 0x7F7F7F7F);                     \
    acc[1][1] = __builtin_amdgcn_mfma_scale_f32_32x32x64_f8f6f4(                      \
        fa1, fb1, acc[1][1], 0, 0, 0, 0x7F7F7F7F, 0, 0x7F7F7F7F);                     \
    acc[2][1] = __builtin_amdgcn_mfma_scale_f32_32x32x64_f8f6f4(                      \
        fa2, fb1, acc[2][1], 0, 0, 0, 0x7F7F7F7F, 0, 0x7F7F7F7F);                     \
    acc[3][1] = __builtin_amdgcn_mfma_scale_f32_32x32x64_f8f6f4(                      \
        fa3, fb1, acc[3][1], 0, 0, 0, 0x7F7F7F7F, 0, 0x7F7F7F7F);                     \
    __builtin_amdgcn_s_setprio(0);                                                    \
  } while (0)

__device__ __forceinline__ i32x8 rd_frag2(const char* p) {
    i32x4 lo = *(const i32x4*)(p);
    i32x4 hi = *(const i32x4*)(p + 1024);
    return __builtin_shufflevector(lo, hi, 0, 1, 2, 3, 4, 5, 6, 7);
}

__global__ __launch_bounds__(512, 2) void gemm_max_kernel(
    const unsigned char* __restrict__ A, const unsigned char* __restrict__ V,
    float* __restrict__ rowmax) {
    __shared__ __align__(1024) char smem[131072];

    const int tid = threadIdx.x;
    const int l   = tid & 63;
    const int wid = tid >> 6;
    const int wm  = wid >> 2;      // 0..1 : 128-row half of A tile
    const int wn  = wid & 3;       // 0..3 : 64-col slice of B tile
    const int lo5 = l & 31;
    const int hi  = l >> 5;
    const int l16 = l * 16;

    const int bx  = blockIdx.x;                  // 2048 blocks, %8==0 -> bijective
    const int swz = (bx & 7) * 256 + (bx >> 3);  // XCD-aware swizzle
    const int rowBlk = swz >> 5;                 // 0..63
    const int clip   = swz & 31;                 // 0..31
    const size_t aRow0 = (size_t)rowBlk * 256;
    const size_t vRow0 = (size_t)clip * 256;

    // staging sources (per-lane permutation; see layout comment):
    //   A slot s=tid: row = ((tid>>7)&3)*32 + (tid&31), kb = ((tid>>5)&1)*32
    //                 + ((tid>>6)&1)*16 ; slot tid+512 = +128 rows (+98304 B)
    //   B slot s=tid: row = (tid>>8)*64 + ((tid>>7)&1)*32 + (tid&31), same kb
    const int rowA = ((tid >> 7) & 3) * 32 + (tid & 31);
    const int rowB = (tid >> 8) * 64 + ((tid >> 7) & 1) * 32 + (tid & 31);
    const int kbT  = ((tid >> 5) & 1) * 32 + ((tid >> 6) & 1) * 16;
    const unsigned char* aStage = A + (aRow0 + rowA) * 768 + kbT;
    const unsigned char* vStage = V + (vRow0 + rowB) * 768 + kbT;

    f32x16 acc[4][2];
#pragma unroll
    for (int i = 0; i < 4; ++i)
#pragma unroll
        for (int j = 0; j < 2; ++j)
#pragma unroll
            for (int r = 0; r < 16; ++r) acc[i][j][r] = 0.0f;

    i32x8 fa0, fa1, fa2, fa3, fb0, fb1;

    // prologue: stage tiles 0..3 (16 loads/thread, oldest-first = tiles 0,1 first)
    STAGE(0); STAGE(1); STAGE(2); STAGE(3);

#pragma unroll 1
    for (int j = 0; j < 6; ++j) {
        const int T = 2 * j;
        // entry: wait the stage issued 2 iterations back (tiles T,T+1); keep the
        // newer 8 loads (tiles T+2,T+3) in flight. Last iter: nothing newer -> 0.
        if (j < 5) asm volatile("s_waitcnt vmcnt(8)" ::: "memory");
        else       asm volatile("s_waitcnt vmcnt(0)" ::: "memory");
        __builtin_amdgcn_sched_barrier(0);
        __builtin_amdgcn_s_barrier();           // BAR_A: all waves' stages visible
        __builtin_amdgcn_sched_barrier(0);
        READT(T);
        asm volatile("s_waitcnt lgkmcnt(0)" ::: "memory");
        __builtin_amdgcn_sched_barrier(0);
        MFMA8();                                 // tile T
        __builtin_amdgcn_sched_barrier(0);
        READT(T + 1);                            // latency rides under MFMA pipe
        asm volatile("s_waitcnt lgkmcnt(0)" ::: "memory");
        __builtin_amdgcn_sched_barrier(0);
        __builtin_amdgcn_s_barrier();           // BAR_B: all reads of bufs T,T+1 done
        __builtin_amdgcn_sched_barrier(0);
        MFMA8();                                 // tile T+1
        __builtin_amdgcn_sched_barrier(0);
        if (j < 4) { STAGE(T + 4); STAGE(T + 5); }  // overwrite bufs T&3,(T+1)&3: safe
    }

    // epilogue: fused row-max over the clip's 256 visual cols.
    // C/D layout (32x32): col = lane&31, row = (r&3) + 8*(r>>2) + 4*hi
    __syncthreads();
    float* pm = (float*)smem;  // [256 rows][4 wn] partial maxes
#pragma unroll
    for (int mi = 0; mi < 4; ++mi) {
#pragma unroll
        for (int r = 0; r < 16; ++r) {
            float m = fmaxf(acc[mi][0][r], acc[mi][1][r]);
            m = fmaxf(m, __shfl_xor(m, 1, 64));
            m = fmaxf(m, __shfl_xor(m, 2, 64));
            m = fmaxf(m, __shfl_xor(m, 4, 64));
            m = fmaxf(m, __shfl_xor(m, 8, 64));
            m = fmaxf(m, __shfl_xor(m, 16, 64));
            if (lo5 == 0) {
                const int row = wm * 128 + mi * 32 + 4 * hi + (r & 3) + 8 * (r >> 2);
                pm[row * 4 + wn] = m;
            }
        }
    }
    __syncthreads();
    if (tid < 256) {
        float m = fmaxf(fmaxf(pm[tid * 4], pm[tid * 4 + 1]),
                        fmaxf(pm[tid * 4 + 2], pm[tid * 4 + 3]));
        rowmax[(size_t)clip * 16384 + aRow0 + tid] = m;
    }
}

// ---------- kernel 3: mean over 512 audio rows -> clip_sims[32][32] ----------
// folds 1/temp (x10), 1/512 mean, and 1/1024 fp8 pre-scale compensation (32*32).
__global__ __launch_bounds__(256) void reduce_mean_kernel(const float* __restrict__ rm,
                                                          float* __restrict__ clip) {
    const int b = blockIdx.x >> 5;
    const int c = blockIdx.x & 31;
    const int t = threadIdx.x;
    const float* p = rm + (size_t)c * 16384 + (size_t)b * 512;
    float s = p[t] + p[t + 256];
#pragma unroll
    for (int m = 1; m < 64; m <<= 1) s += __shfl_xor(s, m, 64);
    __shared__ float wsum[4];
    if ((t & 63) == 0) wsum[t >> 6] = s;
    __syncthreads();
    if (t == 0)
        clip[b * 32 + c] = (wsum[0] + wsum[1] + wsum[2] + wsum[3]) * (1.0f / (51.2f * 1024.0f));
}

// ---------- kernel 4: log-softmax both ways on 32x32 + scalar loss ----------
__global__ __launch_bounds__(1024) void finalize_kernel(const float* __restrict__ clip,
                                                        float* __restrict__ out) {
    __shared__ float cs[32][33];
    __shared__ float rlse[32], clse[32];
    const int t = threadIdx.x;
    const int b = t >> 5, c = t & 31;
    cs[b][c] = clip[b * 32 + c];
    __syncthreads();
    if (t < 32) {
        float mx = -1e30f;
        for (int j = 0; j < 32; ++j) mx = fmaxf(mx, cs[t][j]);
        float s = 0.0f;
        for (int j = 0; j < 32; ++j) s += expf(cs[t][j] - mx);
        rlse[t] = mx + logf(s);
    } else if (t < 64) {
        const int cc = t - 32;
        float mx = -1e30f;
        for (int j = 0; j < 32; ++j) mx = fmaxf(mx, cs[j][cc]);
        float s = 0.0f;
        for (int j = 0; j < 32; ++j) s += expf(cs[j][cc] - mx);
        clse[cc] = mx + logf(s);
    }
    __syncthreads();
    if (t == 0) {
        float L = 0.0f;
        for (int i = 0; i < 32; ++i)
            L += -0.5f * (2.0f * cs[i][i] - rlse[i] - clse[i]);
        out[0] = L * (1.0f / 32.0f);
    }
}

extern "C" void kernel_launch(void* const* d_in, const int* in_sizes, int n_in,
                              void* d_out, int out_size, void* d_ws, size_t ws_size,
                              hipStream_t stream) {
    const float* audio  = (const float*)d_in[0];   // (32, 512, 768) f32
    const float* visual = (const float*)d_in[1];   // (32, 256, 768) f32

    unsigned char* aN = (unsigned char*)d_ws;                   // 16384*768 fp8
    unsigned char* vN = aN + (size_t)16384 * 768;               // 8192*768 fp8
    float* rowmax = (float*)(vN + (size_t)8192 * 768);          // 32*16384 f32
    float* clip   = rowmax + (size_t)32 * 16384;                // 1024 f32
    float* out    = (float*)d_out;

    l2norm_fp8_kernel<<<6144, 256, 0, stream>>>(audio, visual, aN);
    gemm_max_kernel<<<2048, 512, 0, stream>>>(aN, vN, rowmax);
    reduce_mean_kernel<<<1024, 256, 0, stream>>>(rowmax, clip);
    finalize_kernel<<<1, 1024, 0, stream>>>(clip, out);
}

// Round 9
// 169.938 us; speedup vs baseline: 1.4768x; 1.4768x over previous
//
#include <hip/hip_runtime.h>

#define GLOBAL_AS __attribute__((address_space(1)))
#define LDS_AS    __attribute__((address_space(3)))

typedef int   i32x4  __attribute__((ext_vector_type(4)));
typedef int   i32x8  __attribute__((ext_vector_type(8)));
typedef float f32x4  __attribute__((ext_vector_type(4)));

// ---------- kernel 1: fused L2 normalize -> fp8 e4m3 of (x * 32 / ||row||) ----------
__global__ __launch_bounds__(256) void l2norm_fp8_kernel(const float* __restrict__ audio,
                                                         const float* __restrict__ visual,
                                                         unsigned char* __restrict__ out) {
    const int gw = blockIdx.x * 4 + (threadIdx.x >> 6);  // global row 0..24575
    const int l  = threadIdx.x & 63;
    const float* src = (gw < 16384) ? (audio + (size_t)gw * 768)
                                    : (visual + ((size_t)gw - 16384) * 768);
    const float4* p = (const float4*)src;
    float4 a = p[l], b = p[l + 64], c = p[l + 128];
    float ss = a.x * a.x + a.y * a.y + a.z * a.z + a.w * a.w
             + b.x * b.x + b.y * b.y + b.z * b.z + b.w * b.w
             + c.x * c.x + c.y * c.y + c.z * c.z + c.w * c.w;
#pragma unroll
    for (int m = 1; m < 64; m <<= 1) ss += __shfl_xor(ss, m, 64);
    const float s = 32.0f / fmaxf(sqrtf(ss), 1e-12f);
    unsigned int* o = (unsigned int*)(out + (size_t)gw * 768);
    int d0 = __builtin_amdgcn_cvt_pk_fp8_f32(a.x * s, a.y * s, 0, false);
    d0     = __builtin_amdgcn_cvt_pk_fp8_f32(a.z * s, a.w * s, d0, true);
    int d1 = __builtin_amdgcn_cvt_pk_fp8_f32(b.x * s, b.y * s, 0, false);
    d1     = __builtin_amdgcn_cvt_pk_fp8_f32(b.z * s, b.w * s, d1, true);
    int d2 = __builtin_amdgcn_cvt_pk_fp8_f32(c.x * s, c.y * s, 0, false);
    d2     = __builtin_amdgcn_cvt_pk_fp8_f32(c.z * s, c.w * s, d2, true);
    o[l] = (unsigned int)d0; o[l + 64] = (unsigned int)d1; o[l + 128] = (unsigned int)d2;
}

// ---------- kernel 2: 128x128-tile fp8 GEMM (mfma_scale 16x16x128), fused row-max ---
// m97/m148-style structure: 256 threads (4 waves, 2wm x 2wn), wave tile 64x64,
// single-buffered 32 KiB LDS, 2 barriers per K-tile, compiler-managed waits,
// ~3 blocks/CU for implicit cross-block latency overlap. K = 768 = 6 x BK(128).
// LDS: A[128 rows][128 B] @0, B same @+16384. Rows are 128 B -> G4 bank swizzle:
//   phys_c = logical_c ^ ((row & 7) << 4)
// Stage: linear LDS dest + inverse-swizzled per-lane GLOBAL source (rule #21).
// NOTE: do NOT raise launch_bounds min-waves past 3: acc(64) + bfrags(32) +
// afrag(8) + addr regs must fit 512/min_waves VGPRs (R5: cap 128 -> spill ->
// 8 GB scratch traffic, 5.5x slower).

__device__ __forceinline__ i32x8 rd_frag(const char* p) {
    // logical 32 B of K: chunk h=0 at p, h=1 at p XOR 16 (row-swizzle is bit4+)
    i32x4 lo = *(const i32x4*)(p);
    i32x4 hi = *(const i32x4*)((const char*)((size_t)p ^ 16));
    return __builtin_shufflevector(lo, hi, 0, 1, 2, 3, 4, 5, 6, 7);
}

__global__ __launch_bounds__(256, 3) void gemm_max_kernel(
    const unsigned char* __restrict__ A, const unsigned char* __restrict__ V,
    float* __restrict__ rowhalf) {
    __shared__ __align__(1024) char smem[32768];

    const int tid = threadIdx.x;
    const int l   = tid & 63;
    const int wid = tid >> 6;
    const int wm  = wid >> 1;      // 0..1 : 64-row half of A tile
    const int wn  = wid & 1;       // 0..1 : 64-col half of B tile
    const int lr  = l & 15;        // row/col within 16
    const int lg  = l >> 4;        // k-group 0..3 (32 B each)

    const int bx  = blockIdx.x;                   // 8192 blocks, %8==0 -> bijective
    const int swz = (bx & 7) * 1024 + (bx >> 3);  // XCD-aware swizzle
    const int rowBlk = swz >> 6;                  // 0..127
    const int colBlk = swz & 63;                  // 0..63 (clip = colBlk>>1)
    const size_t aRow0 = (size_t)rowBlk * 128;
    const size_t vRow0 = (size_t)colBlk * 128;

    // staging source: LDS linear offset o (row=o>>7, c=o&127) <- global element
    // (row, c ^ ((row&7)<<4)). Thread t, chunk q: o = q*4096 + t*16 ->
    // row = q*32 + (t>>3) (q*32 keeps row&7), c = (t&7)*16.
    const int srow = tid >> 3;                                    // 0..31
    const int scol = ((tid & 7) * 16) ^ ((srow & 7) << 4);
    const unsigned char* aStage = A + (aRow0 + srow) * 768 + scol;
    const unsigned char* vStage = V + (vRow0 + srow) * 768 + scol;

    // reader per-lane base: row-part lr*128, col c0 = (lg*32) ^ ((l&7)<<4)
    const int c0    = (lg * 32) ^ ((l & 7) << 4);
    const int aBase = wm * 8192 + lr * 128 + c0;          // + mi*2048
    const int bBase = 16384 + wn * 8192 + lr * 128 + c0;  // + ni*2048

    f32x4 acc[4][4];
#pragma unroll
    for (int i = 0; i < 4; ++i)
#pragma unroll
        for (int j = 0; j < 4; ++j) {
            acc[i][j][0] = 0.0f; acc[i][j][1] = 0.0f;
            acc[i][j][2] = 0.0f; acc[i][j][3] = 0.0f;
        }

#pragma unroll 1
    for (int kt = 0; kt < 6; ++kt) {
        __syncthreads();  // previous tile's reads done before overwrite
        const size_t ko = (size_t)kt * 128;
#pragma unroll
        for (int q = 0; q < 4; ++q) {
            __builtin_amdgcn_global_load_lds(
                (GLOBAL_AS void*)(aStage + ko + (size_t)q * 24576),
                (LDS_AS void*)(smem + q * 4096 + tid * 16), 16, 0, 0);
        }
#pragma unroll
        for (int q = 0; q < 4; ++q) {
            __builtin_amdgcn_global_load_lds(
                (GLOBAL_AS void*)(vStage + ko + (size_t)q * 24576),
                (LDS_AS void*)(smem + 16384 + q * 4096 + tid * 16), 16, 0, 0);
        }
        __syncthreads();  // compiler drains vmcnt(0) before barrier -> tile ready

        i32x8 fb[4];
#pragma unroll
        for (int ni = 0; ni < 4; ++ni) fb[ni] = rd_frag(smem + bBase + ni * 2048);
#pragma unroll
        for (int mi = 0; mi < 4; ++mi) {
            const i32x8 fav = rd_frag(smem + aBase + mi * 2048);
#pragma unroll
            for (int ni = 0; ni < 4; ++ni)
                acc[mi][ni] = __builtin_amdgcn_mfma_scale_f32_16x16x128_f8f6f4(
                    fav, fb[ni], acc[mi][ni], 0, 0, 0, 0x7F7F7F7F, 0, 0x7F7F7F7F);
        }
    }

    // epilogue: fused row-max over this block's 128 visual cols.
    // C/D layout (16x16): col = lane&15, row = (lane>>4)*4 + reg  (m89; shape-
    // determined for f8f6f4-scaled too)
    __syncthreads();
    float* pm = (float*)smem;  // [128 rows][2 wn]
#pragma unroll
    for (int mi = 0; mi < 4; ++mi) {
#pragma unroll
        for (int j = 0; j < 4; ++j) {
            float m = fmaxf(fmaxf(acc[mi][0][j], acc[mi][1][j]),
                            fmaxf(acc[mi][2][j], acc[mi][3][j]));
            m = fmaxf(m, __shfl_xor(m, 1, 64));
            m = fmaxf(m, __shfl_xor(m, 2, 64));
            m = fmaxf(m, __shfl_xor(m, 4, 64));
            m = fmaxf(m, __shfl_xor(m, 8, 64));
            if (lr == 0) {
                const int row = wm * 64 + mi * 16 + lg * 4 + j;
                pm[row * 2 + wn] = m;
            }
        }
    }
    __syncthreads();
    if (tid < 128) {
        float m = fmaxf(pm[tid * 2], pm[tid * 2 + 1]);
        rowhalf[(size_t)colBlk * 16384 + aRow0 + tid] = m;
    }
}

// ---------- kernel 3: combine halves (max) + mean over 512 rows -> clip_sims ----------
// folds 1/temp (x10), 1/512 mean, and 1/1024 fp8 pre-scale compensation (32*32).
__global__ __launch_bounds__(256) void reduce_mean_kernel(const float* __restrict__ rh,
                                                          float* __restrict__ clip) {
    const int b = blockIdx.x >> 5;
    const int c = blockIdx.x & 31;
    const int t = threadIdx.x;
    const float* p0 = rh + (size_t)(c * 2) * 16384 + (size_t)b * 512;
    const float* p1 = p0 + 16384;
    float s = fmaxf(p0[t], p1[t]) + fmaxf(p0[t + 256], p1[t + 256]);
#pragma unroll
    for (int m = 1; m < 64; m <<= 1) s += __shfl_xor(s, m, 64);
    __shared__ float wsum[4];
    if ((t & 63) == 0) wsum[t >> 6] = s;
    __syncthreads();
    if (t == 0)
        clip[b * 32 + c] = (wsum[0] + wsum[1] + wsum[2] + wsum[3]) * (1.0f / (51.2f * 1024.0f));
}

// ---------- kernel 4: log-softmax both ways on 32x32 + scalar loss ----------
__global__ __launch_bounds__(1024) void finalize_kernel(const float* __restrict__ clip,
                                                        float* __restrict__ out) {
    __shared__ float cs[32][33];
    __shared__ float rlse[32], clse[32];
    const int t = threadIdx.x;
    const int b = t >> 5, c = t & 31;
    cs[b][c] = clip[b * 32 + c];
    __syncthreads();
    if (t < 32) {
        float mx = -1e30f;
        for (int j = 0; j < 32; ++j) mx = fmaxf(mx, cs[t][j]);
        float s = 0.0f;
        for (int j = 0; j < 32; ++j) s += expf(cs[t][j] - mx);
        rlse[t] = mx + logf(s);
    } else if (t < 64) {
        const int cc = t - 32;
        float mx = -1e30f;
        for (int j = 0; j < 32; ++j) mx = fmaxf(mx, cs[j][cc]);
        float s = 0.0f;
        for (int j = 0; j < 32; ++j) s += expf(cs[j][cc] - mx);
        clse[cc] = mx + logf(s);
    }
    __syncthreads();
    if (t == 0) {
        float L = 0.0f;
        for (int i = 0; i < 32; ++i)
            L += -0.5f * (2.0f * cs[i][i] - rlse[i] - clse[i]);
        out[0] = L * (1.0f / 32.0f);
    }
}

extern "C" void kernel_launch(void* const* d_in, const int* in_sizes, int n_in,
                              void* d_out, int out_size, void* d_ws, size_t ws_size,
                              hipStream_t stream) {
    const float* audio  = (const float*)d_in[0];   // (32, 512, 768) f32
    const float* visual = (const float*)d_in[1];   // (32, 256, 768) f32

    unsigned char* aN = (unsigned char*)d_ws;                   // 16384*768 fp8
    unsigned char* vN = aN + (size_t)16384 * 768;               // 8192*768 fp8
    float* rowhalf = (float*)(vN + (size_t)8192 * 768);         // 64*16384 f32
    float* clip    = rowhalf + (size_t)64 * 16384;              // 1024 f32
    float* out     = (float*)d_out;

    l2norm_fp8_kernel<<<6144, 256, 0, stream>>>(audio, visual, aN);
    gemm_max_kernel<<<8192, 256, 0, stream>>>(aN, vN, rowhalf);
    reduce_mean_kernel<<<1024, 256, 0, stream>>>(rowhalf, clip);
    finalize_kernel<<<1, 1024, 0, stream>>>(clip, out);
}